// Round 2
// baseline (259.348 us; speedup 1.0000x reference)
//
#include <hip/hip_runtime.h>
#include <hip/hip_bf16.h>
#include <math.h>

#define BATCH 4
#define NQ 8192
#define KNB 8
#define K1 9            // keep 9 per partition: self filtered at merge
#define STRIDE 8        // warmup subsample stride (1 of every 8 candidates)
#define CAP 63          // survivor buffer entries per thread (63KB LDS @ 256 thr)
#define IDXMASK 8191u
#define KEYMASK 0xFFFFE000u  // keep sign+exp+10 mantissa bits, low 13 bits hold index

// sorted insert of packed key into ascending nk[0..K1-1]
#define CHAIN9(KEY) { unsigned kk = (KEY); \
  _Pragma("unroll") \
  for (int j = 0; j < K1; ++j) { \
    unsigned lo = min(kk, nk[j]); unsigned hi = max(kk, nk[j]); \
    nk[j] = lo; kk = hi; } }

// drain survivor buffer through the chain, tighten theta
#define DRAIN() { \
  for (int i = 0; i < cnt; ++i) { \
    unsigned key = sbuf[base + i]; \
    if (key < nk[K1-1]) CHAIN9(key); \
  } \
  cnt = 0; \
  theta = __uint_as_float((nk[K1-1] & KEYMASK) | 0x1FFFu); }

__global__ __launch_bounds__(256) void knn_kernel(
    const float* __restrict__ pc, unsigned* __restrict__ wsK,
    int P, int cpp)
{
  __shared__ unsigned sbuf[256 * CAP];
  const int b = blockIdx.y;
  const int p = blockIdx.z;
  const int q = blockIdx.x * 256 + threadIdx.x;
  const float* __restrict__ px = pc + (size_t)b * 3 * NQ;
  const float* __restrict__ py = px + NQ;
  const float* __restrict__ pz = px + 2 * NQ;
  const float qx = px[q], qy = py[q], qz = pz[q];

  unsigned nk[K1];
#pragma unroll
  for (int j = 0; j < K1; ++j) nk[j] = 0xFFFFFFFFu;

  const int c0 = p * cpp;
  const int nblk = cpp / STRIDE;

  // ---- warmup: chain-insert the stride-8 subsample (t = c0 + j*8) ----
  for (int j = 0; j < nblk; ++j) {
    const int t = c0 + j * STRIDE;
    float dx = qx - px[t], dy = qy - py[t], dz = qz - pz[t];
    float d = dx * dx + dy * dy + dz * dz;
    unsigned key = (__float_as_uint(d) & KEYMASK) | (unsigned)t;
    if (key < nk[K1 - 1]) CHAIN9(key);
  }

  // conservative float gate: top of nk[8]'s truncation bucket
  float theta = __uint_as_float((nk[K1 - 1] & KEYMASK) | 0x1FFFu);
  int cnt = 0;
  const unsigned base = (unsigned)threadIdx.x * CAP;

  // ---- gated scan over the remaining 7/8 candidates ----
  for (int j = 0; j < nblk; ++j) {
    const int t0 = c0 + j * STRIDE;
#pragma unroll
    for (int u = 1; u < STRIDE; ++u) {
      const int t = t0 + u;
      float dx = qx - px[t], dy = qy - py[t], dz = qz - pz[t];
      float d = dx * dx + dy * dy + dz * dz;
      if (d <= theta) {
        sbuf[base + cnt] = (__float_as_uint(d) & KEYMASK) | (unsigned)t;
        cnt++;
      }
    }
    // collective drain: all lanes drain together when any is nearly full
    if (__any(cnt >= CAP - (STRIDE - 1))) {
      DRAIN();
    }
  }
  DRAIN();

  size_t o = ((size_t)((b * NQ + q) * P + p)) * K1;
#pragma unroll
  for (int j = 0; j < K1; ++j) wsK[o + j] = nk[j];
}

__global__ __launch_bounds__(256) void loss_kernel(
    const float* __restrict__ pc, const float* __restrict__ pf,
    const unsigned* __restrict__ wsK, float* __restrict__ acc, int P)
{
  const int b = blockIdx.y;
  const int q = blockIdx.x * 256 + threadIdx.x;
  const float* __restrict__ px = pc + (size_t)b * 3 * NQ;
  const float* __restrict__ py = px + NQ;
  const float* __restrict__ pz = px + 2 * NQ;
  const float* __restrict__ fx = pf + (size_t)b * 3 * NQ;
  const float* __restrict__ fy = fx + NQ;
  const float* __restrict__ fz = fx + 2 * NQ;

  unsigned nk[KNB];
#pragma unroll
  for (int j = 0; j < KNB; ++j) nk[j] = 0xFFFFFFFFu;

  const size_t o = (size_t)((b * NQ + q) * P) * K1;
  const int total = P * K1;
  for (int m = 0; m < total; ++m) {
    unsigned key = wsK[o + m];
    if ((key & IDXMASK) == (unsigned)q) continue;  // drop self
    if (key < nk[KNB - 1]) {
      unsigned kk = key;
#pragma unroll
      for (int j = 0; j < KNB; ++j) {
        unsigned lo = min(kk, nk[j]); unsigned hi = max(kk, nk[j]);
        nk[j] = lo; kk = hi;
      }
    }
  }

  const float qx = px[q], qy = py[q], qz = pz[q];
  const float fqx = fx[q], fqy = fy[q], fqz = fz[q];
  float ssum = 0.f, sdsum = 0.f;
#pragma unroll
  for (int j = 0; j < KNB; ++j) {
    int i = (int)(nk[j] & IDXMASK);
    // recompute exact distance (key truncation never affects the values)
    float dx = qx - px[i], dy = qy - py[i], dz = qz - pz[i];
    float d = dx * dx + dy * dy + dz * dz;
    float e = expf(expf(-2.0f * d));  // exp(exp(-d/alpha)), alpha=0.5
    float gx = fx[i] - fqx, gy = fy[i] - fqy, gz = fz[i] - fqz;
    float diff = sqrtf(gx * gx + gy * gy + gz * gz);
    ssum += e; sdsum += e * diff;
  }

  // wave reduce (wave64)
  for (int off = 32; off > 0; off >>= 1) {
    ssum += __shfl_down(ssum, off);
    sdsum += __shfl_down(sdsum, off);
  }
  __shared__ float r[8];
  const int lane = threadIdx.x & 63, wid = threadIdx.x >> 6;
  if (lane == 0) { r[wid * 2] = ssum; r[wid * 2 + 1] = sdsum; }
  __syncthreads();
  if (threadIdx.x == 0) {
    float s0 = r[0] + r[2] + r[4] + r[6];
    float s1 = r[1] + r[3] + r[5] + r[7];
    atomicAdd(&acc[b * 2 + 0], s0);
    atomicAdd(&acc[b * 2 + 1], s1);
  }
}

__global__ void final_kernel(const float* __restrict__ acc, float* __restrict__ out)
{
  if (threadIdx.x == 0) {
    float s = 0.f;
    for (int b = 0; b < BATCH; ++b) s += acc[b * 2 + 1] / acc[b * 2];
    out[0] = s * (1.0f / BATCH);
  }
}

extern "C" void kernel_launch(void* const* d_in, const int* in_sizes, int n_in,
                              void* d_out, int out_size, void* d_ws, size_t ws_size,
                              hipStream_t stream) {
  const float* pc = (const float*)d_in[0];   // pc1:      (4,3,8192) f32
  const float* pf = (const float*)d_in[1];   // pred_flow:(4,3,8192) f32
  float* out = (float*)d_out;                // scalar f32
  float* acc = (float*)d_ws;                 // 8 floats: per-batch {sum_e, sum_e_diff}
  unsigned* wsK = (unsigned*)((char*)d_ws + 256);

  const size_t needP4 = 256 + (size_t)BATCH * NQ * 4 * K1 * sizeof(unsigned);
  const int P = (ws_size >= needP4) ? 4 : 1;
  const int cpp = NQ / P;

  hipMemsetAsync(d_ws, 0, 256, stream);  // zero accumulators

  dim3 g1(NQ / 256, BATCH, P);
  knn_kernel<<<g1, 256, 0, stream>>>(pc, wsK, P, cpp);

  dim3 g2(NQ / 256, BATCH);
  loss_kernel<<<g2, 256, 0, stream>>>(pc, pf, wsK, acc, P);

  final_kernel<<<1, 64, 0, stream>>>(acc, out);
}

// Round 3
// 172.301 us; speedup vs baseline: 1.5052x; 1.5052x over previous
//
#include <hip/hip_runtime.h>
#include <hip/hip_bf16.h>
#include <math.h>

#define BATCH 4
#define NQ 8192
#define KNB 8
#define K1 9            // keep 9 per partition: self filtered at merge
#define TILE 1024       // candidates staged per LDS chunk
#define WARM 256        // warmup candidates (branchless chain) to establish theta
#define CAP 25          // survivor buffer entries per thread (odd -> conflict-free)
#define IDXMASK 8191u
#define KEYMASK 0xFFFFE000u  // keep sign+exp+10 mantissa bits, low 13 bits hold index

// branchless sorted insert of packed key into ascending nk[0..K1-1]:
// if key >= nk[K1-1] the chain is naturally a no-op (key falls out the bottom)
#define CHAIN9(KEY) { unsigned kk = (KEY); \
  _Pragma("unroll") \
  for (int j = 0; j < K1; ++j) { \
    unsigned lo = min(kk, nk[j]); unsigned hi = max(kk, nk[j]); \
    nk[j] = lo; kk = hi; } }

// drain survivor buffer through the chain, tighten theta
#define DRAIN() { \
  for (int i = 0; i < cnt; ++i) { \
    unsigned key = sbuf[base + i]; \
    if (key < nk[K1-1]) CHAIN9(key); \
  } \
  cnt = 0; \
  theta = __uint_as_float((nk[K1-1] & KEYMASK) | 0x1FFFu); }

// branchless gated push: unconditional store, conditional increment
#define GPROC(VX, VY, VZ, CIDX) { \
  float dx = qx - (VX); float dy = qy - (VY); float dz = qz - (VZ); \
  float d = dx*dx + dy*dy + dz*dz; \
  sbuf[base + cnt] = (__float_as_uint(d) & KEYMASK) | (unsigned)(CIDX); \
  cnt += (d <= theta) ? 1 : 0; }

__global__ __launch_bounds__(256) void knn_kernel(
    const float* __restrict__ pc, unsigned* __restrict__ wsK,
    int P, int cpp)
{
  __shared__ float sx[TILE], sy[TILE], sz[TILE];
  __shared__ unsigned sbuf[256 * CAP];
  const int b = blockIdx.y;
  const int p = blockIdx.z;
  const int q = blockIdx.x * 256 + threadIdx.x;
  const float* __restrict__ px = pc + (size_t)b * 3 * NQ;
  const float* __restrict__ py = px + NQ;
  const float* __restrict__ pz = px + 2 * NQ;
  const float qx = px[q], qy = py[q], qz = pz[q];

  unsigned nk[K1];
#pragma unroll
  for (int j = 0; j < K1; ++j) nk[j] = 0xFFFFFFFFu;

  const unsigned base = (unsigned)threadIdx.x * CAP;
  int cnt = 0;
  float theta = 0.f;
  const int c0 = p * cpp;

  for (int t0 = 0; t0 < cpp; t0 += TILE) {
    __syncthreads();
    {
      const float4* gx = (const float4*)(px + c0 + t0);
      const float4* gy = (const float4*)(py + c0 + t0);
      const float4* gz = (const float4*)(pz + c0 + t0);
      float4* lx = (float4*)sx; float4* ly = (float4*)sy; float4* lz = (float4*)sz;
      for (int i = threadIdx.x; i < TILE / 4; i += 256) {
        lx[i] = gx[i]; ly[i] = gy[i]; lz[i] = gz[i];
      }
    }
    __syncthreads();

    int start4 = 0;
    if (t0 == 0) {
      // ---- warmup: unconditional branchless chain over first WARM ----
      for (int i = 0; i < WARM; ++i) {
        float dx = qx - sx[i], dy = qy - sy[i], dz = qz - sz[i];
        float d = dx * dx + dy * dy + dz * dz;
        unsigned key = (__float_as_uint(d) & KEYMASK) | (unsigned)(c0 + i);
        CHAIN9(key);
      }
      theta = __uint_as_float((nk[K1 - 1] & KEYMASK) | 0x1FFFu);
      start4 = WARM / 4;
    }

    const float4* sx4 = (const float4*)sx;
    const float4* sy4 = (const float4*)sy;
    const float4* sz4 = (const float4*)sz;
    for (int i4 = start4; i4 < TILE / 4; ++i4) {
      if (__any(cnt >= CAP - 4)) { DRAIN(); }
      float4 vx = sx4[i4], vy = sy4[i4], vz = sz4[i4];
      int cb = c0 + t0 + i4 * 4;
      GPROC(vx.x, vy.x, vz.x, cb + 0);
      GPROC(vx.y, vy.y, vz.y, cb + 1);
      GPROC(vx.z, vy.z, vz.z, cb + 2);
      GPROC(vx.w, vy.w, vz.w, cb + 3);
    }
  }
  DRAIN();

  size_t o = ((size_t)((b * NQ + q) * P + p)) * K1;
#pragma unroll
  for (int j = 0; j < K1; ++j) wsK[o + j] = nk[j];
}

__global__ __launch_bounds__(256) void loss_kernel(
    const float* __restrict__ pc, const float* __restrict__ pf,
    const unsigned* __restrict__ wsK, float* __restrict__ acc, int P)
{
  const int b = blockIdx.y;
  const int q = blockIdx.x * 256 + threadIdx.x;
  const float* __restrict__ px = pc + (size_t)b * 3 * NQ;
  const float* __restrict__ py = px + NQ;
  const float* __restrict__ pz = px + 2 * NQ;
  const float* __restrict__ fx = pf + (size_t)b * 3 * NQ;
  const float* __restrict__ fy = fx + NQ;
  const float* __restrict__ fz = fx + 2 * NQ;

  unsigned nk[KNB];
#pragma unroll
  for (int j = 0; j < KNB; ++j) nk[j] = 0xFFFFFFFFu;

  const size_t o = (size_t)((b * NQ + q) * P) * K1;
  const int total = P * K1;
  for (int m = 0; m < total; ++m) {
    unsigned key = wsK[o + m];
    if ((key & IDXMASK) == (unsigned)q) continue;  // drop self
    if (key < nk[KNB - 1]) {
      unsigned kk = key;
#pragma unroll
      for (int j = 0; j < KNB; ++j) {
        unsigned lo = min(kk, nk[j]); unsigned hi = max(kk, nk[j]);
        nk[j] = lo; kk = hi;
      }
    }
  }

  const float qx = px[q], qy = py[q], qz = pz[q];
  const float fqx = fx[q], fqy = fy[q], fqz = fz[q];
  float ssum = 0.f, sdsum = 0.f;
#pragma unroll
  for (int j = 0; j < KNB; ++j) {
    int i = (int)(nk[j] & IDXMASK);
    // recompute exact distance (key truncation never affects the values)
    float dx = qx - px[i], dy = qy - py[i], dz = qz - pz[i];
    float d = dx * dx + dy * dy + dz * dz;
    float e = expf(expf(-2.0f * d));  // exp(exp(-d/alpha)), alpha=0.5
    float gx = fx[i] - fqx, gy = fy[i] - fqy, gz = fz[i] - fqz;
    float diff = sqrtf(gx * gx + gy * gy + gz * gz);
    ssum += e; sdsum += e * diff;
  }

  // wave reduce (wave64)
  for (int off = 32; off > 0; off >>= 1) {
    ssum += __shfl_down(ssum, off);
    sdsum += __shfl_down(sdsum, off);
  }
  __shared__ float r[8];
  const int lane = threadIdx.x & 63, wid = threadIdx.x >> 6;
  if (lane == 0) { r[wid * 2] = ssum; r[wid * 2 + 1] = sdsum; }
  __syncthreads();
  if (threadIdx.x == 0) {
    float s0 = r[0] + r[2] + r[4] + r[6];
    float s1 = r[1] + r[3] + r[5] + r[7];
    atomicAdd(&acc[b * 2 + 0], s0);
    atomicAdd(&acc[b * 2 + 1], s1);
  }
}

__global__ void final_kernel(const float* __restrict__ acc, float* __restrict__ out)
{
  if (threadIdx.x == 0) {
    float s = 0.f;
    for (int b = 0; b < BATCH; ++b) s += acc[b * 2 + 1] / acc[b * 2];
    out[0] = s * (1.0f / BATCH);
  }
}

extern "C" void kernel_launch(void* const* d_in, const int* in_sizes, int n_in,
                              void* d_out, int out_size, void* d_ws, size_t ws_size,
                              hipStream_t stream) {
  const float* pc = (const float*)d_in[0];   // pc1:      (4,3,8192) f32
  const float* pf = (const float*)d_in[1];   // pred_flow:(4,3,8192) f32
  float* out = (float*)d_out;                // scalar f32
  float* acc = (float*)d_ws;                 // 8 floats: per-batch {sum_e, sum_e_diff}
  unsigned* wsK = (unsigned*)((char*)d_ws + 256);

  const size_t needP4 = 256 + (size_t)BATCH * NQ * 4 * K1 * sizeof(unsigned);
  const int P = (ws_size >= needP4) ? 4 : 1;
  const int cpp = NQ / P;

  hipMemsetAsync(d_ws, 0, 256, stream);  // zero accumulators

  dim3 g1(NQ / 256, BATCH, P);
  knn_kernel<<<g1, 256, 0, stream>>>(pc, wsK, P, cpp);

  dim3 g2(NQ / 256, BATCH);
  loss_kernel<<<g2, 256, 0, stream>>>(pc, pf, wsK, acc, P);

  final_kernel<<<1, 64, 0, stream>>>(acc, out);
}

// Round 4
// 153.589 us; speedup vs baseline: 1.6886x; 1.1218x over previous
//
#include <hip/hip_runtime.h>
#include <hip/hip_bf16.h>
#include <math.h>

#define BATCH 4
#define NQ 8192
#define KNB 8
#define K1 9            // keep 9 per partition: self filtered at merge
#define TILE 1024       // candidates staged per LDS chunk
#define CAP 25          // survivor buffer entries per thread (odd -> 2-way = free)
#define THSAMP 256      // theta subsample size per theta-partition
#define SPART 2         // theta partitions (disjoint subsamples, min-merged)
#define IDXMASK 8191u
#define KEYMASK 0xFFFFE000u  // keep sign+exp+10 mantissa bits, low 13 bits hold index

// branchless sorted insert into ascending nk[0..K1-1] (no-op if key falls out bottom)
#define CHAIN9(KEY) { unsigned kk = (KEY); \
  _Pragma("unroll") \
  for (int j = 0; j < K1; ++j) { \
    unsigned lo = min(kk, nk[j]); unsigned hi = max(kk, nk[j]); \
    nk[j] = lo; kk = hi; } }

// drain survivor buffer through the chain, tighten theta (uint domain, monotone)
#define DRAIN() { \
  for (int i = 0; i < cnt; ++i) { \
    unsigned key = sbuf[base + i]; \
    if (key < nk[K1-1]) CHAIN9(key); \
  } \
  cnt = 0; \
  thetaU = min(thetaU, nk[K1-1] | 0x1FFFu); }

// branchless gated push: unconditional store, conditional increment (uint compare)
#define GPROC(VX, VY, VZ, CIDX) { \
  float dx = qx - (VX); float dy = qy - (VY); float dz = qz - (VZ); \
  float d = dx*dx + dy*dy + dz*dz; \
  unsigned du = __float_as_uint(d); \
  sbuf[base + cnt] = (du & KEYMASK) | (unsigned)(CIDX); \
  cnt += (du <= thetaU) ? 1 : 0; }

// ---- theta bound: 9th-of-256-subsample per query, two disjoint subsamples ----
__global__ __launch_bounds__(256) void theta_kernel(
    const float* __restrict__ pc, unsigned* __restrict__ thetaOut)
{
  __shared__ float swx[THSAMP], swy[THSAMP], swz[THSAMP];
  const int b = blockIdx.y, p = blockIdx.z;
  const int q = blockIdx.x * 256 + threadIdx.x;
  const float* __restrict__ px = pc + (size_t)b * 3 * NQ;
  const float* __restrict__ py = px + NQ;
  const float* __restrict__ pz = px + 2 * NQ;
  const int tid = threadIdx.x;
  const int si = tid * (NQ / THSAMP) + p * (NQ / THSAMP / SPART);
  swx[tid] = px[si]; swy[tid] = py[si]; swz[tid] = pz[si];
  __syncthreads();
  const float qx = px[q], qy = py[q], qz = pz[q];
  unsigned nk[K1];
#pragma unroll
  for (int j = 0; j < K1; ++j) nk[j] = 0xFFFFFFFFu;
  for (int i = 0; i < THSAMP; ++i) {
    float dx = qx - swx[i], dy = qy - swy[i], dz = qz - swz[i];
    float d = dx * dx + dy * dy + dz * dz;
    CHAIN9(__float_as_uint(d));  // raw distance bits; idx not needed for the bound
  }
  // bucket-top of subset 9th: valid upper bound on every true top-9 key
  thetaOut[(size_t)(b * NQ + q) * SPART + p] = nk[K1 - 1] | 0x1FFFu;
}

__global__ __launch_bounds__(256) void knn_kernel(
    const float* __restrict__ pc, const unsigned* __restrict__ thetaIn,
    unsigned* __restrict__ wsK, int P, int cpp)
{
  __shared__ float sx[TILE], sy[TILE], sz[TILE];
  __shared__ unsigned sbuf[256 * CAP];
  const int b = blockIdx.y;
  const int p = blockIdx.z;
  const int q = blockIdx.x * 256 + threadIdx.x;
  const float* __restrict__ px = pc + (size_t)b * 3 * NQ;
  const float* __restrict__ py = px + NQ;
  const float* __restrict__ pz = px + 2 * NQ;
  const float qx = px[q], qy = py[q], qz = pz[q];

  uint2 th = ((const uint2*)thetaIn)[b * NQ + q];
  unsigned thetaU = min(th.x, th.y);

  unsigned nk[K1];
#pragma unroll
  for (int j = 0; j < K1; ++j) nk[j] = 0xFFFFFFFFu;

  const unsigned base = (unsigned)threadIdx.x * CAP;
  int cnt = 0;
  const int c0 = p * cpp;

  for (int t0 = 0; t0 < cpp; t0 += TILE) {
    __syncthreads();
    {
      const float4* gx = (const float4*)(px + c0 + t0);
      const float4* gy = (const float4*)(py + c0 + t0);
      const float4* gz = (const float4*)(pz + c0 + t0);
      float4* lx = (float4*)sx; float4* ly = (float4*)sy; float4* lz = (float4*)sz;
      for (int i = threadIdx.x; i < TILE / 4; i += 256) {
        lx[i] = gx[i]; ly[i] = gy[i]; lz[i] = gz[i];
      }
    }
    __syncthreads();

    const float4* sx4 = (const float4*)sx;
    const float4* sy4 = (const float4*)sy;
    const float4* sz4 = (const float4*)sz;
    for (int i4 = 0; i4 < TILE / 4; i4 += 2) {   // 8 candidates per overflow check
      if (__any(cnt >= CAP - 8)) { DRAIN(); }
      float4 vx = sx4[i4], vy = sy4[i4], vz = sz4[i4];
      int cb = c0 + t0 + i4 * 4;
      GPROC(vx.x, vy.x, vz.x, cb + 0);
      GPROC(vx.y, vy.y, vz.y, cb + 1);
      GPROC(vx.z, vy.z, vz.z, cb + 2);
      GPROC(vx.w, vy.w, vz.w, cb + 3);
      vx = sx4[i4 + 1]; vy = sy4[i4 + 1]; vz = sz4[i4 + 1];
      GPROC(vx.x, vy.x, vz.x, cb + 4);
      GPROC(vx.y, vy.y, vz.y, cb + 5);
      GPROC(vx.z, vy.z, vz.z, cb + 6);
      GPROC(vx.w, vy.w, vz.w, cb + 7);
    }
  }
  DRAIN();

  size_t o = ((size_t)((b * NQ + q) * P + p)) * K1;
#pragma unroll
  for (int j = 0; j < K1; ++j) wsK[o + j] = nk[j];
}

__global__ __launch_bounds__(256) void loss_kernel(
    const float* __restrict__ pc, const float* __restrict__ pf,
    const unsigned* __restrict__ wsK, float* __restrict__ acc, int P)
{
  const int b = blockIdx.y;
  const int q = blockIdx.x * 256 + threadIdx.x;
  const float* __restrict__ px = pc + (size_t)b * 3 * NQ;
  const float* __restrict__ py = px + NQ;
  const float* __restrict__ pz = px + 2 * NQ;
  const float* __restrict__ fx = pf + (size_t)b * 3 * NQ;
  const float* __restrict__ fy = fx + NQ;
  const float* __restrict__ fz = fx + 2 * NQ;

  unsigned nk[KNB];
#pragma unroll
  for (int j = 0; j < KNB; ++j) nk[j] = 0xFFFFFFFFu;

  const size_t o = (size_t)((b * NQ + q) * P) * K1;
  const int total = P * K1;
  for (int m = 0; m < total; ++m) {
    unsigned key = wsK[o + m];
    if ((key & IDXMASK) == (unsigned)q) continue;  // drop self
    if (key < nk[KNB - 1]) {
      unsigned kk = key;
#pragma unroll
      for (int j = 0; j < KNB; ++j) {
        unsigned lo = min(kk, nk[j]); unsigned hi = max(kk, nk[j]);
        nk[j] = lo; kk = hi;
      }
    }
  }

  const float qx = px[q], qy = py[q], qz = pz[q];
  const float fqx = fx[q], fqy = fy[q], fqz = fz[q];
  float ssum = 0.f, sdsum = 0.f;
#pragma unroll
  for (int j = 0; j < KNB; ++j) {
    int i = (int)(nk[j] & IDXMASK);
    // recompute exact distance (key truncation never affects the values)
    float dx = qx - px[i], dy = qy - py[i], dz = qz - pz[i];
    float d = dx * dx + dy * dy + dz * dz;
    float e = expf(expf(-2.0f * d));  // exp(exp(-d/alpha)), alpha=0.5
    float gx = fx[i] - fqx, gy = fy[i] - fqy, gz = fz[i] - fqz;
    float diff = sqrtf(gx * gx + gy * gy + gz * gz);
    ssum += e; sdsum += e * diff;
  }

  // wave reduce (wave64)
  for (int off = 32; off > 0; off >>= 1) {
    ssum += __shfl_down(ssum, off);
    sdsum += __shfl_down(sdsum, off);
  }
  __shared__ float r[8];
  const int lane = threadIdx.x & 63, wid = threadIdx.x >> 6;
  if (lane == 0) { r[wid * 2] = ssum; r[wid * 2 + 1] = sdsum; }
  __syncthreads();
  if (threadIdx.x == 0) {
    float s0 = r[0] + r[2] + r[4] + r[6];
    float s1 = r[1] + r[3] + r[5] + r[7];
    atomicAdd(&acc[b * 2 + 0], s0);
    atomicAdd(&acc[b * 2 + 1], s1);
  }
}

__global__ void final_kernel(const float* __restrict__ acc, float* __restrict__ out)
{
  if (threadIdx.x == 0) {
    float s = 0.f;
    for (int b = 0; b < BATCH; ++b) s += acc[b * 2 + 1] / acc[b * 2];
    out[0] = s * (1.0f / BATCH);
  }
}

extern "C" void kernel_launch(void* const* d_in, const int* in_sizes, int n_in,
                              void* d_out, int out_size, void* d_ws, size_t ws_size,
                              hipStream_t stream) {
  const float* pc = (const float*)d_in[0];   // pc1:      (4,3,8192) f32
  const float* pf = (const float*)d_in[1];   // pred_flow:(4,3,8192) f32
  float* out = (float*)d_out;                // scalar f32
  float* acc = (float*)d_ws;                 // 8 floats: per-batch {sum_e, sum_e_diff}
  unsigned* thetaBuf = (unsigned*)((char*)d_ws + 256);
  const size_t thetaBytes = (size_t)BATCH * NQ * SPART * sizeof(unsigned);  // 256 KB
  unsigned* wsK = (unsigned*)((char*)d_ws + 256 + thetaBytes);

  const size_t needP8 = 256 + thetaBytes + (size_t)BATCH * NQ * 8 * K1 * sizeof(unsigned);
  const size_t needP4 = 256 + thetaBytes + (size_t)BATCH * NQ * 4 * K1 * sizeof(unsigned);
  const int P = (ws_size >= needP8) ? 8 : ((ws_size >= needP4) ? 4 : 1);
  const int cpp = NQ / P;

  hipMemsetAsync(d_ws, 0, 256, stream);  // zero accumulators

  dim3 g0(NQ / 256, BATCH, SPART);
  theta_kernel<<<g0, 256, 0, stream>>>(pc, thetaBuf);

  dim3 g1(NQ / 256, BATCH, P);
  knn_kernel<<<g1, 256, 0, stream>>>(pc, thetaBuf, wsK, P, cpp);

  dim3 g2(NQ / 256, BATCH);
  loss_kernel<<<g2, 256, 0, stream>>>(pc, pf, wsK, acc, P);

  final_kernel<<<1, 64, 0, stream>>>(acc, out);
}

// Round 5
// 134.318 us; speedup vs baseline: 1.9309x; 1.1435x over previous
//
#include <hip/hip_runtime.h>
#include <hip/hip_bf16.h>
#include <math.h>

#define BATCH 4
#define NQ 8192
#define KNB 8
#define K1 9            // keep 9 per partition: self filtered at merge
#define TILE 1024       // candidates staged per LDS chunk (== cpp at P=8)
#define CAP 24          // u16 survivor entries per thread
#define THSAMP 256      // theta subsample size per theta-partition
#define SPART 2         // theta partitions (disjoint subsamples, min-merged)
#define IDXMASK 8191u
#define KEYMASK 0xFFFFE000u  // keep sign+exp+10 mantissa bits, low 13 bits hold index
#define EPS_S 1e-3f     // gate slack >> fp32 error of the 3-fma score form

// branchless sorted insert into ascending nk[0..K1-1]
#define CHAIN9(KEY) { unsigned kk = (KEY); \
  _Pragma("unroll") \
  for (int j = 0; j < K1; ++j) { \
    unsigned lo = min(kk, nk[j]); unsigned hi = max(kk, nk[j]); \
    nk[j] = lo; kk = hi; } }

// drain survivors: recompute EXACT keys (R1-identical arithmetic) from the
// live LDS tile, chain them, tighten the score gate
#define DRAIN(T0) { \
  for (int i = 0; i < cnt; ++i) { \
    int j = sbuf[base + i]; \
    float dx = qx - sx[j], dy = qy - sy[j], dz = qz - sz[j]; \
    float d = dx*dx + dy*dy + dz*dz; \
    unsigned key = (__float_as_uint(d) & KEYMASK) | (unsigned)(c0 + (T0) + j); \
    if (key < nk[K1-1]) CHAIN9(key); \
  } \
  cnt = 0; \
  if (nk[K1-1] != 0xFFFFFFFFu) { \
    float td = __uint_as_float(nk[K1-1] | 0x1FFFu); \
    thetaS = fminf(thetaS, 0.5f*(td - qq) + EPS_S); \
  } }

// survivor push: exec-masked (rare) store of tile-local u16 index
#define GPROC(SS, JLOCAL) { \
  if ((SS) <= thetaS) { sbuf[base + cnt] = (unsigned short)(JLOCAL); cnt++; } }

// ---- theta bound (9th-of-256-subsample, x2 disjoint) + h = 0.5*||c||^2 ----
__global__ __launch_bounds__(256) void theta_kernel(
    const float* __restrict__ pc, unsigned* __restrict__ thetaOut,
    float* __restrict__ hOut)
{
  __shared__ float swx[THSAMP], swy[THSAMP], swz[THSAMP];
  const int b = blockIdx.y, p = blockIdx.z;
  const int q = blockIdx.x * 256 + threadIdx.x;
  const float* __restrict__ px = pc + (size_t)b * 3 * NQ;
  const float* __restrict__ py = px + NQ;
  const float* __restrict__ pz = px + 2 * NQ;
  const int tid = threadIdx.x;
  const int si = tid * (NQ / THSAMP) + p * (NQ / THSAMP / SPART);
  swx[tid] = px[si]; swy[tid] = py[si]; swz[tid] = pz[si];
  __syncthreads();
  const float qx = px[q], qy = py[q], qz = pz[q];
  if (p == 0) hOut[b * NQ + q] = 0.5f * (qx*qx + qy*qy + qz*qz);
  unsigned nk[K1];
#pragma unroll
  for (int j = 0; j < K1; ++j) nk[j] = 0xFFFFFFFFu;
  for (int i = 0; i < THSAMP; ++i) {
    float dx = qx - swx[i], dy = qy - swy[i], dz = qz - swz[i];
    float d = dx * dx + dy * dy + dz * dz;
    CHAIN9(__float_as_uint(d));
  }
  thetaOut[(size_t)(b * NQ + q) * SPART + p] = nk[K1 - 1] | 0x1FFFu;
}

__global__ __launch_bounds__(256) void knn_kernel(
    const float* __restrict__ pc, const float* __restrict__ hB,
    const unsigned* __restrict__ thetaIn, unsigned* __restrict__ wsK,
    int P, int cpp)
{
  __shared__ float sx[TILE], sy[TILE], sz[TILE], sh[TILE];
  __shared__ unsigned short sbuf[256 * CAP];
  const int b = blockIdx.y;
  const int p = blockIdx.z;
  const int q = blockIdx.x * 256 + threadIdx.x;
  const float* __restrict__ px = pc + (size_t)b * 3 * NQ;
  const float* __restrict__ py = px + NQ;
  const float* __restrict__ pz = px + 2 * NQ;
  const float* __restrict__ ph = hB + (size_t)b * NQ;
  const float qx = px[q], qy = py[q], qz = pz[q];
  const float nqx = -qx, nqy = -qy, nqz = -qz;
  const float qq = qx*qx + qy*qy + qz*qz;

  uint2 th = ((const uint2*)thetaIn)[b * NQ + q];
  float thetaS = 0.5f * (__uint_as_float(min(th.x, th.y)) - qq) + EPS_S;

  unsigned nk[K1];
#pragma unroll
  for (int j = 0; j < K1; ++j) nk[j] = 0xFFFFFFFFu;

  const unsigned base = (unsigned)threadIdx.x * CAP;
  int cnt = 0;
  const int c0 = p * cpp;

  for (int t0 = 0; t0 < cpp; t0 += TILE) {
    __syncthreads();
    {
      const float4* gx = (const float4*)(px + c0 + t0);
      const float4* gy = (const float4*)(py + c0 + t0);
      const float4* gz = (const float4*)(pz + c0 + t0);
      const float4* gh = (const float4*)(ph + c0 + t0);
      float4* lx = (float4*)sx; float4* ly = (float4*)sy;
      float4* lz = (float4*)sz; float4* lh = (float4*)sh;
      for (int i = threadIdx.x; i < TILE / 4; i += 256) {
        lx[i] = gx[i]; ly[i] = gy[i]; lz[i] = gz[i]; lh[i] = gh[i];
      }
    }
    __syncthreads();

    const float4* sx4 = (const float4*)sx;
    const float4* sy4 = (const float4*)sy;
    const float4* sz4 = (const float4*)sz;
    const float4* sh4 = (const float4*)sh;
    for (int i4 = 0; i4 < TILE / 4; i4 += 2) {   // 8 candidates per overflow check
      if (__any(cnt >= CAP - 8)) { DRAIN(t0); }
      float4 X = sx4[i4], Y = sy4[i4], Z = sz4[i4], H = sh4[i4];
      const int jb = i4 * 4;
      float s0 = fmaf(nqx, X.x, fmaf(nqy, Y.x, fmaf(nqz, Z.x, H.x)));
      float s1 = fmaf(nqx, X.y, fmaf(nqy, Y.y, fmaf(nqz, Z.y, H.y)));
      float s2 = fmaf(nqx, X.z, fmaf(nqy, Y.z, fmaf(nqz, Z.z, H.z)));
      float s3 = fmaf(nqx, X.w, fmaf(nqy, Y.w, fmaf(nqz, Z.w, H.w)));
      GPROC(s0, jb + 0); GPROC(s1, jb + 1);
      GPROC(s2, jb + 2); GPROC(s3, jb + 3);
      X = sx4[i4 + 1]; Y = sy4[i4 + 1]; Z = sz4[i4 + 1]; H = sh4[i4 + 1];
      float s4 = fmaf(nqx, X.x, fmaf(nqy, Y.x, fmaf(nqz, Z.x, H.x)));
      float s5 = fmaf(nqx, X.y, fmaf(nqy, Y.y, fmaf(nqz, Z.y, H.y)));
      float s6 = fmaf(nqx, X.z, fmaf(nqy, Y.z, fmaf(nqz, Z.z, H.z)));
      float s7 = fmaf(nqx, X.w, fmaf(nqy, Y.w, fmaf(nqz, Z.w, H.w)));
      GPROC(s4, jb + 4); GPROC(s5, jb + 5);
      GPROC(s6, jb + 6); GPROC(s7, jb + 7);
    }
    DRAIN(t0);   // drain at tile end while coords are still resident
  }

  size_t o = ((size_t)((b * NQ + q) * P + p)) * K1;
#pragma unroll
  for (int j = 0; j < K1; ++j) wsK[o + j] = nk[j];
}

__global__ __launch_bounds__(256) void loss_kernel(
    const float* __restrict__ pc, const float* __restrict__ pf,
    const unsigned* __restrict__ wsK, float* __restrict__ acc, int P)
{
  const int b = blockIdx.y;
  const int q = blockIdx.x * 256 + threadIdx.x;
  const float* __restrict__ px = pc + (size_t)b * 3 * NQ;
  const float* __restrict__ py = px + NQ;
  const float* __restrict__ pz = px + 2 * NQ;
  const float* __restrict__ fx = pf + (size_t)b * 3 * NQ;
  const float* __restrict__ fy = fx + NQ;
  const float* __restrict__ fz = fx + 2 * NQ;

  unsigned nk[KNB];
#pragma unroll
  for (int j = 0; j < KNB; ++j) nk[j] = 0xFFFFFFFFu;

  const size_t o = (size_t)((b * NQ + q) * P) * K1;
  const int total = P * K1;
  for (int m = 0; m < total; ++m) {
    unsigned key = wsK[o + m];
    if ((key & IDXMASK) == (unsigned)q) continue;  // drop self
    if (key < nk[KNB - 1]) {
      unsigned kk = key;
#pragma unroll
      for (int j = 0; j < KNB; ++j) {
        unsigned lo = min(kk, nk[j]); unsigned hi = max(kk, nk[j]);
        nk[j] = lo; kk = hi;
      }
    }
  }

  const float qx = px[q], qy = py[q], qz = pz[q];
  const float fqx = fx[q], fqy = fy[q], fqz = fz[q];
  float ssum = 0.f, sdsum = 0.f;
#pragma unroll
  for (int j = 0; j < KNB; ++j) {
    int i = (int)(nk[j] & IDXMASK);
    float dx = qx - px[i], dy = qy - py[i], dz = qz - pz[i];
    float d = dx * dx + dy * dy + dz * dz;
    float e = expf(expf(-2.0f * d));  // exp(exp(-d/alpha)), alpha=0.5
    float gx = fx[i] - fqx, gy = fy[i] - fqy, gz = fz[i] - fqz;
    float diff = sqrtf(gx * gx + gy * gy + gz * gz);
    ssum += e; sdsum += e * diff;
  }

  for (int off = 32; off > 0; off >>= 1) {
    ssum += __shfl_down(ssum, off);
    sdsum += __shfl_down(sdsum, off);
  }
  __shared__ float r[8];
  const int lane = threadIdx.x & 63, wid = threadIdx.x >> 6;
  if (lane == 0) { r[wid * 2] = ssum; r[wid * 2 + 1] = sdsum; }
  __syncthreads();
  if (threadIdx.x == 0) {
    float s0 = r[0] + r[2] + r[4] + r[6];
    float s1 = r[1] + r[3] + r[5] + r[7];
    atomicAdd(&acc[b * 2 + 0], s0);
    atomicAdd(&acc[b * 2 + 1], s1);
  }
}

__global__ void final_kernel(const float* __restrict__ acc, float* __restrict__ out)
{
  if (threadIdx.x == 0) {
    float s = 0.f;
    for (int b = 0; b < BATCH; ++b) s += acc[b * 2 + 1] / acc[b * 2];
    out[0] = s * (1.0f / BATCH);
  }
}

extern "C" void kernel_launch(void* const* d_in, const int* in_sizes, int n_in,
                              void* d_out, int out_size, void* d_ws, size_t ws_size,
                              hipStream_t stream) {
  const float* pc = (const float*)d_in[0];   // pc1:      (4,3,8192) f32
  const float* pf = (const float*)d_in[1];   // pred_flow:(4,3,8192) f32
  float* out = (float*)d_out;                // scalar f32
  float* acc = (float*)d_ws;                 // 8 floats: per-batch {sum_e, sum_e_diff}
  const size_t thetaBytes = (size_t)BATCH * NQ * SPART * sizeof(unsigned);  // 256 KB
  const size_t hBytes = (size_t)BATCH * NQ * sizeof(float);                 // 128 KB
  unsigned* thetaBuf = (unsigned*)((char*)d_ws + 256);
  float* hBuf = (float*)((char*)d_ws + 256 + thetaBytes);
  unsigned* wsK = (unsigned*)((char*)d_ws + 256 + thetaBytes + hBytes);

  const size_t fixed = 256 + thetaBytes + hBytes;
  const size_t needP8 = fixed + (size_t)BATCH * NQ * 8 * K1 * sizeof(unsigned);
  const size_t needP4 = fixed + (size_t)BATCH * NQ * 4 * K1 * sizeof(unsigned);
  const int P = (ws_size >= needP8) ? 8 : ((ws_size >= needP4) ? 4 : 1);
  const int cpp = NQ / P;

  hipMemsetAsync(d_ws, 0, 256, stream);  // zero accumulators

  dim3 g0(NQ / 256, BATCH, SPART);
  theta_kernel<<<g0, 256, 0, stream>>>(pc, thetaBuf, hBuf);

  dim3 g1(NQ / 256, BATCH, P);
  knn_kernel<<<g1, 256, 0, stream>>>(pc, hBuf, thetaBuf, wsK, P, cpp);

  dim3 g2(NQ / 256, BATCH);
  loss_kernel<<<g2, 256, 0, stream>>>(pc, pf, wsK, acc, P);

  final_kernel<<<1, 64, 0, stream>>>(acc, out);
}

// Round 6
// 134.206 us; speedup vs baseline: 1.9325x; 1.0008x over previous
//
#include <hip/hip_runtime.h>
#include <hip/hip_bf16.h>
#include <math.h>

#define BATCH 4
#define NQ 8192
#define KNB 8
#define K1 9            // keep 9 per partition: self filtered at merge
#define TILE 1024       // candidates staged per LDS chunk (== cpp at P=8)
#define CAP 32          // u16 survivor entries per thread
#define THSAMP 256      // theta subsample size per theta-partition
#define SPART 2         // theta partitions (disjoint subsamples, min-merged)
#define IDXMASK 8191u
#define KEYMASK 0xFFFFE000u  // keep sign+exp+10 mantissa bits, low 13 bits hold index
#define EPS_S 1e-3f     // gate slack >> fp32 error of the 3-fma score form

// branchless sorted insert into ascending nk[0..K1-1]
#define CHAIN9(KEY) { unsigned kk = (KEY); \
  _Pragma("unroll") \
  for (int j = 0; j < K1; ++j) { \
    unsigned lo = min(kk, nk[j]); unsigned hi = max(kk, nk[j]); \
    nk[j] = lo; kk = hi; } }

// drain survivors: recompute EXACT keys (R1-identical arithmetic) from the
// live LDS tile, chain them, tighten the score gate
#define DRAIN(T0) { \
  for (int i = 0; i < cnt; ++i) { \
    int j = sbuf[base + i]; \
    float dx = qx - sx[j], dy = qy - sy[j], dz = qz - sz[j]; \
    float d = dx*dx + dy*dy + dz*dz; \
    unsigned key = (__float_as_uint(d) & KEYMASK) | (unsigned)(c0 + (T0) + j); \
    if (key < nk[K1-1]) CHAIN9(key); \
  } \
  cnt = 0; \
  if (nk[K1-1] != 0xFFFFFFFFu) { \
    float td = __uint_as_float(nk[K1-1] | 0x1FFFu); \
    thetaS = fminf(thetaS, 0.5f*(td - qq) + EPS_S); \
  } }

// survivor push: exec-masked (rare) store of tile-local u16 index
#define GPROC(SS, JLOCAL) { \
  if ((SS) <= thetaS) { sbuf[base + cnt] = (unsigned short)(JLOCAL); cnt++; } }

// 4 scores from one float4 quad
#define SCORE4(S0,S1,S2,S3, X,Y,Z,H) \
  float S0 = fmaf(nqx, X.x, fmaf(nqy, Y.x, fmaf(nqz, Z.x, H.x))); \
  float S1 = fmaf(nqx, X.y, fmaf(nqy, Y.y, fmaf(nqz, Z.y, H.y))); \
  float S2 = fmaf(nqx, X.z, fmaf(nqy, Y.z, fmaf(nqz, Z.z, H.z))); \
  float S3 = fmaf(nqx, X.w, fmaf(nqy, Y.w, fmaf(nqz, Z.w, H.w)));

// ---- theta bound (9th-of-256-subsample, x2 disjoint) + h = 0.5*||c||^2 ----
__global__ __launch_bounds__(256) void theta_kernel(
    const float* __restrict__ pc, unsigned* __restrict__ thetaOut,
    float* __restrict__ hOut)
{
  __shared__ float swx[THSAMP], swy[THSAMP], swz[THSAMP];
  const int b = blockIdx.y, p = blockIdx.z;
  const int q = blockIdx.x * 256 + threadIdx.x;
  const float* __restrict__ px = pc + (size_t)b * 3 * NQ;
  const float* __restrict__ py = px + NQ;
  const float* __restrict__ pz = px + 2 * NQ;
  const int tid = threadIdx.x;
  const int si = tid * (NQ / THSAMP) + p * (NQ / THSAMP / SPART);
  swx[tid] = px[si]; swy[tid] = py[si]; swz[tid] = pz[si];
  __syncthreads();
  const float qx = px[q], qy = py[q], qz = pz[q];
  if (p == 0) hOut[b * NQ + q] = 0.5f * (qx*qx + qy*qy + qz*qz);
  unsigned nk[K1];
#pragma unroll
  for (int j = 0; j < K1; ++j) nk[j] = 0xFFFFFFFFu;
  for (int i = 0; i < THSAMP; ++i) {
    float dx = qx - swx[i], dy = qy - swy[i], dz = qz - swz[i];
    float d = dx * dx + dy * dy + dz * dz;
    CHAIN9(__float_as_uint(d));
  }
  thetaOut[(size_t)(b * NQ + q) * SPART + p] = nk[K1 - 1] | 0x1FFFu;
}

__global__ __launch_bounds__(256) void knn_kernel(
    const float* __restrict__ pc, const float* __restrict__ hB,
    const unsigned* __restrict__ thetaIn, unsigned* __restrict__ wsK,
    int P, int cpp)
{
  __shared__ float sx[TILE], sy[TILE], sz[TILE], sh[TILE];
  __shared__ unsigned short sbuf[256 * CAP];
  const int b = blockIdx.y;
  const int p = blockIdx.z;
  const int q = blockIdx.x * 256 + threadIdx.x;
  const float* __restrict__ px = pc + (size_t)b * 3 * NQ;
  const float* __restrict__ py = px + NQ;
  const float* __restrict__ pz = px + 2 * NQ;
  const float* __restrict__ ph = hB + (size_t)b * NQ;
  const float qx = px[q], qy = py[q], qz = pz[q];
  const float nqx = -qx, nqy = -qy, nqz = -qz;
  const float qq = qx*qx + qy*qy + qz*qz;

  uint2 th = ((const uint2*)thetaIn)[b * NQ + q];
  float thetaS = 0.5f * (__uint_as_float(min(th.x, th.y)) - qq) + EPS_S;

  unsigned nk[K1];
#pragma unroll
  for (int j = 0; j < K1; ++j) nk[j] = 0xFFFFFFFFu;

  const unsigned base = (unsigned)threadIdx.x * CAP;
  int cnt = 0;
  const int c0 = p * cpp;

  for (int t0 = 0; t0 < cpp; t0 += TILE) {
    __syncthreads();
    {
      const float4* gx = (const float4*)(px + c0 + t0);
      const float4* gy = (const float4*)(py + c0 + t0);
      const float4* gz = (const float4*)(pz + c0 + t0);
      const float4* gh = (const float4*)(ph + c0 + t0);
      float4* lx = (float4*)sx; float4* ly = (float4*)sy;
      float4* lz = (float4*)sz; float4* lh = (float4*)sh;
      for (int i = threadIdx.x; i < TILE / 4; i += 256) {
        lx[i] = gx[i]; ly[i] = gy[i]; lz[i] = gz[i]; lh[i] = gh[i];
      }
    }
    __syncthreads();

    const float4* sx4 = (const float4*)sx;
    const float4* sy4 = (const float4*)sy;
    const float4* sz4 = (const float4*)sz;
    const float4* sh4 = (const float4*)sh;
    for (int i16 = 0; i16 < TILE / 16; ++i16) {
      if (__any(cnt >= CAP - 16)) { DRAIN(t0); }
      const int i4 = i16 * 4;
      const int jb = i16 * 16;
      // issue all 16 tile loads before any use -> deep lgkm pipeline
      float4 X0 = sx4[i4], X1 = sx4[i4+1], X2 = sx4[i4+2], X3 = sx4[i4+3];
      float4 Y0 = sy4[i4], Y1 = sy4[i4+1], Y2 = sy4[i4+2], Y3 = sy4[i4+3];
      float4 Z0 = sz4[i4], Z1 = sz4[i4+1], Z2 = sz4[i4+2], Z3 = sz4[i4+3];
      float4 H0 = sh4[i4], H1 = sh4[i4+1], H2 = sh4[i4+2], H3 = sh4[i4+3];
      SCORE4(s0, s1, s2, s3, X0, Y0, Z0, H0);
      SCORE4(s4, s5, s6, s7, X1, Y1, Z1, H1);
      SCORE4(s8, s9, sa, sb, X2, Y2, Z2, H2);
      SCORE4(sc, sd, se, sf, X3, Y3, Z3, H3);
      GPROC(s0, jb + 0);  GPROC(s1, jb + 1);  GPROC(s2, jb + 2);  GPROC(s3, jb + 3);
      GPROC(s4, jb + 4);  GPROC(s5, jb + 5);  GPROC(s6, jb + 6);  GPROC(s7, jb + 7);
      GPROC(s8, jb + 8);  GPROC(s9, jb + 9);  GPROC(sa, jb + 10); GPROC(sb, jb + 11);
      GPROC(sc, jb + 12); GPROC(sd, jb + 13); GPROC(se, jb + 14); GPROC(sf, jb + 15);
    }
    DRAIN(t0);   // drain at tile end while coords are still resident
  }

  // transposed layout: [(b,p,j)][q] -> coalesced store here, coalesced read in loss
  const size_t qo = (size_t)b * NQ + q;
#pragma unroll
  for (int j = 0; j < K1; ++j)
    wsK[((size_t)(b * P + p) * K1 + j) * NQ + q] = nk[j];
}

__global__ __launch_bounds__(256) void loss_kernel(
    const float* __restrict__ pc, const float* __restrict__ pf,
    const unsigned* __restrict__ wsK, float* __restrict__ acc, int P)
{
  const int b = blockIdx.y;
  const int q = blockIdx.x * 256 + threadIdx.x;
  const float* __restrict__ px = pc + (size_t)b * 3 * NQ;
  const float* __restrict__ py = px + NQ;
  const float* __restrict__ pz = px + 2 * NQ;
  const float* __restrict__ fx = pf + (size_t)b * 3 * NQ;
  const float* __restrict__ fy = fx + NQ;
  const float* __restrict__ fz = fx + 2 * NQ;

  unsigned nk[KNB];
#pragma unroll
  for (int j = 0; j < KNB; ++j) nk[j] = 0xFFFFFFFFu;

  const int total = P * K1;
  for (int m = 0; m < total; ++m) {
    unsigned key = wsK[((size_t)b * P * K1 + m) * NQ + q];  // coalesced
    if ((key & IDXMASK) == (unsigned)q) continue;  // drop self
    if (key < nk[KNB - 1]) {
      unsigned kk = key;
#pragma unroll
      for (int j = 0; j < KNB; ++j) {
        unsigned lo = min(kk, nk[j]); unsigned hi = max(kk, nk[j]);
        nk[j] = lo; kk = hi;
      }
    }
  }

  const float qx = px[q], qy = py[q], qz = pz[q];
  const float fqx = fx[q], fqy = fy[q], fqz = fz[q];
  float ssum = 0.f, sdsum = 0.f;
#pragma unroll
  for (int j = 0; j < KNB; ++j) {
    int i = (int)(nk[j] & IDXMASK);
    float dx = qx - px[i], dy = qy - py[i], dz = qz - pz[i];
    float d = dx * dx + dy * dy + dz * dz;
    float e = expf(expf(-2.0f * d));  // exp(exp(-d/alpha)), alpha=0.5
    float gx = fx[i] - fqx, gy = fy[i] - fqy, gz = fz[i] - fqz;
    float diff = sqrtf(gx * gx + gy * gy + gz * gz);
    ssum += e; sdsum += e * diff;
  }

  for (int off = 32; off > 0; off >>= 1) {
    ssum += __shfl_down(ssum, off);
    sdsum += __shfl_down(sdsum, off);
  }
  __shared__ float r[8];
  const int lane = threadIdx.x & 63, wid = threadIdx.x >> 6;
  if (lane == 0) { r[wid * 2] = ssum; r[wid * 2 + 1] = sdsum; }
  __syncthreads();
  if (threadIdx.x == 0) {
    float s0 = r[0] + r[2] + r[4] + r[6];
    float s1 = r[1] + r[3] + r[5] + r[7];
    atomicAdd(&acc[b * 2 + 0], s0);
    atomicAdd(&acc[b * 2 + 1], s1);
  }
}

__global__ void final_kernel(const float* __restrict__ acc, float* __restrict__ out)
{
  if (threadIdx.x == 0) {
    float s = 0.f;
    for (int b = 0; b < BATCH; ++b) s += acc[b * 2 + 1] / acc[b * 2];
    out[0] = s * (1.0f / BATCH);
  }
}

extern "C" void kernel_launch(void* const* d_in, const int* in_sizes, int n_in,
                              void* d_out, int out_size, void* d_ws, size_t ws_size,
                              hipStream_t stream) {
  const float* pc = (const float*)d_in[0];   // pc1:      (4,3,8192) f32
  const float* pf = (const float*)d_in[1];   // pred_flow:(4,3,8192) f32
  float* out = (float*)d_out;                // scalar f32
  float* acc = (float*)d_ws;                 // 8 floats: per-batch {sum_e, sum_e_diff}
  const size_t thetaBytes = (size_t)BATCH * NQ * SPART * sizeof(unsigned);  // 256 KB
  const size_t hBytes = (size_t)BATCH * NQ * sizeof(float);                 // 128 KB
  unsigned* thetaBuf = (unsigned*)((char*)d_ws + 256);
  float* hBuf = (float*)((char*)d_ws + 256 + thetaBytes);
  unsigned* wsK = (unsigned*)((char*)d_ws + 256 + thetaBytes + hBytes);

  const size_t fixed = 256 + thetaBytes + hBytes;
  const size_t needP8 = fixed + (size_t)BATCH * NQ * 8 * K1 * sizeof(unsigned);
  const size_t needP4 = fixed + (size_t)BATCH * NQ * 4 * K1 * sizeof(unsigned);
  const int P = (ws_size >= needP8) ? 8 : ((ws_size >= needP4) ? 4 : 1);
  const int cpp = NQ / P;

  hipMemsetAsync(d_ws, 0, 256, stream);  // zero accumulators

  dim3 g0(NQ / 256, BATCH, SPART);
  theta_kernel<<<g0, 256, 0, stream>>>(pc, thetaBuf, hBuf);

  dim3 g1(NQ / 256, BATCH, P);
  knn_kernel<<<g1, 256, 0, stream>>>(pc, hBuf, thetaBuf, wsK, P, cpp);

  dim3 g2(NQ / 256, BATCH);
  loss_kernel<<<g2, 256, 0, stream>>>(pc, pf, wsK, acc, P);

  final_kernel<<<1, 64, 0, stream>>>(acc, out);
}